// Round 10
// baseline (219.284 us; speedup 1.0000x reference)
//
#include <hip/hip_runtime.h>

#define B_  8
#define TQ  256
#define TV  512
#define DD  256

__device__ __forceinline__ float fast_exp2(float x) {
#if __has_builtin(__builtin_amdgcn_exp2f)
  return __builtin_amdgcn_exp2f(x);
#else
  return __exp2f(x);
#endif
}
__device__ __forceinline__ float fast_rcp(float x) {
#if __has_builtin(__builtin_amdgcn_rcpf)
  return __builtin_amdgcn_rcpf(x);
#else
  return 1.0f / x;
#endif
}

// ---------------------------------------------------------------------------
// Fused projections with EXP epilogue (identical to rounds 8/9 — validated):
//   Eq = exp2(SC*(query@W1 + b1)),  Ev = exp2(SC*(value@W2 + b2))
// ---------------------------------------------------------------------------
__global__ __launch_bounds__(256) void proj_fused(
    const float* __restrict__ query, const float* __restrict__ value,
    const float* __restrict__ W1, const float* __restrict__ b1,
    const float* __restrict__ W2, const float* __restrict__ b2,
    float* __restrict__ qp, float* __restrict__ vp, float scale) {
  __shared__ float As[2][32][64];  // [p][k][m ^ sw(k)]
  __shared__ float Bs[2][32][64];  // [p][k][n]
  const int t  = threadIdx.x;
  const int rt = blockIdx.x;
  const int bn = blockIdx.y << 6;

  const float* A; const float* W; const float* bias; float* out; int row0;
  if (rt < 32) { row0 = rt << 6;        A = query; W = W1; bias = b1; out = qp; }
  else         { row0 = (rt - 32) << 6; A = value; W = W2; bias = b2; out = vp; }

  const int tx = t & 15, ty = t >> 4;
  const int aar = t >> 3, aac = (t & 7) << 2;
  const int bbr = t >> 4, bbc = (t & 15) << 2;

  float4 ra[2], rb[2];
#pragma unroll
  for (int it = 0; it < 2; ++it) {
    ra[it] = *(const float4*)(A + (size_t)(row0 + (it << 5) + aar) * DD + aac);
    rb[it] = *(const float4*)(W + (size_t)((it << 4) + bbr) * DD + bn + bbc);
  }
#pragma unroll
  for (int it = 0; it < 2; ++it) {
    const int m = (it << 5) + aar;
#pragma unroll
    for (int c = 0; c < 4; ++c) {
      const int k = aac + c;
      As[0][k][m ^ (((k >> 2) & 7) << 2)] = (&ra[it].x)[c];
    }
    *(float4*)&Bs[0][(it << 4) + bbr][bbc] = rb[it];
  }
  __syncthreads();

  float acc[4][4] = {{0.f,0.f,0.f,0.f},{0.f,0.f,0.f,0.f},
                     {0.f,0.f,0.f,0.f},{0.f,0.f,0.f,0.f}};
  int p = 0;

  for (int k0 = 0; k0 < 256; k0 += 32) {
    const bool more = (k0 + 32) < 256;
    if (more) {
#pragma unroll
      for (int it = 0; it < 2; ++it) {
        ra[it] = *(const float4*)(A + (size_t)(row0 + (it << 5) + aar) * DD + k0 + 32 + aac);
        rb[it] = *(const float4*)(W + (size_t)(k0 + 32 + (it << 4) + bbr) * DD + bn + bbc);
      }
    }
#pragma unroll
    for (int k = 0; k < 32; ++k) {
      float4 aq = *(const float4*)&As[p][k][(ty << 2) ^ (((k >> 2) & 7) << 2)];
      float4 bq = *(const float4*)&Bs[p][k][tx << 2];
      acc[0][0] = fmaf(aq.x, bq.x, acc[0][0]); acc[0][1] = fmaf(aq.x, bq.y, acc[0][1]);
      acc[0][2] = fmaf(aq.x, bq.z, acc[0][2]); acc[0][3] = fmaf(aq.x, bq.w, acc[0][3]);
      acc[1][0] = fmaf(aq.y, bq.x, acc[1][0]); acc[1][1] = fmaf(aq.y, bq.y, acc[1][1]);
      acc[1][2] = fmaf(aq.y, bq.z, acc[1][2]); acc[1][3] = fmaf(aq.y, bq.w, acc[1][3]);
      acc[2][0] = fmaf(aq.z, bq.x, acc[2][0]); acc[2][1] = fmaf(aq.z, bq.y, acc[2][1]);
      acc[2][2] = fmaf(aq.z, bq.z, acc[2][2]); acc[2][3] = fmaf(aq.z, bq.w, acc[2][3]);
      acc[3][0] = fmaf(aq.w, bq.x, acc[3][0]); acc[3][1] = fmaf(aq.w, bq.y, acc[3][1]);
      acc[3][2] = fmaf(aq.w, bq.z, acc[3][2]); acc[3][3] = fmaf(aq.w, bq.w, acc[3][3]);
    }
    if (more) {
      const int q = p ^ 1;
#pragma unroll
      for (int it = 0; it < 2; ++it) {
        const int m = (it << 5) + aar;
#pragma unroll
        for (int c = 0; c < 4; ++c) {
          const int k = aac + c;
          As[q][k][m ^ (((k >> 2) & 7) << 2)] = (&ra[it].x)[c];
        }
        *(float4*)&Bs[q][(it << 4) + bbr][bbc] = rb[it];
      }
      __syncthreads();
      p = q;
    }
  }

  float4 bvv = *(const float4*)&bias[bn + (tx << 2)];
#pragma unroll
  for (int r = 0; r < 4; ++r) {
    float4 o;
    o.x = fast_exp2(scale * (acc[r][0] + bvv.x));
    o.y = fast_exp2(scale * (acc[r][1] + bvv.y));
    o.z = fast_exp2(scale * (acc[r][2] + bvv.z));
    o.w = fast_exp2(scale * (acc[r][3] + bvv.w));
    *(float4*)(out + (size_t)(row0 + (ty << 2) + r) * DD + bn + (tx << 2)) = o;
  }
}

// ---------------------------------------------------------------------------
// Fused score + softmax + context + concat + transposed alignment.
// 1024 blocks x 512 threads (8 waves), 2 q-rows per block.
// LDS = single 512x20 buffer = 40960 B -> 4 blocks/CU x 8 waves = 32
// waves/CU (the occupancy cap; was 16). __launch_bounds__(512,8) caps VGPR
// at 64 (round 9 used 52). Thread t's lane owns j = t for the whole loop.
// 16 sub-chunks of 16 d, single-buffered: issue next loads FIRST (regs
// r0..r3, liveness across 2 barriers — r9-proven no-spill), compute current,
// barrier, write, barrier. q reads wave-uniform -> scalar path, no q LDS.
// Context phase j-split: thread (f = t&255, jh = t>>8) covers 256 j's for
// BOTH rows (value slab read once per block), partials combined via LDS.
// Math (Eq,Ev; x = Eq*Ev): tanh sum via quad-rcp; score = 256 - 2*S.
// ---------------------------------------------------------------------------
__global__ __launch_bounds__(512, 8) void attn_kernel(
    const float* __restrict__ qp, const float* __restrict__ vp,
    const float* __restrict__ value, const float* __restrict__ query,
    float* __restrict__ out1, float* __restrict__ out2) {
  __shared__ float vs[512 * 20];  // 40960 B; aliased as alg[2][512] + part after loop
  float* alg = vs;                 // alg[i*512 + j], 1024 words
  float* part = vs + 2048;         // part[jh*512 + row*256 + f], 1024 words

  const int t    = threadIdx.x;
  const int lane = t & 63;
  const int wv   = t >> 6;        // 0..7
  const int bb   = blockIdx.x & 7;          // batch -> XCD locality
  const int i0   = (blockIdx.x >> 3) << 1;  // first of this block's 2 q-rows

  const float* vpb = vp + (size_t)bb * TV * DD;
  const float* qb  = qp + (size_t)(bb * TQ + i0) * DD;  // wave-uniform reads

  const int sj = t >> 2;          // staging row base 0..127
  const int sc = (t & 3) << 2;    // staging col 0/4/8/12 (64B per lane-quad)

  float acc0 = 0.f, acc1 = 0.f;

  // stage sub-chunk 0
#pragma unroll
  for (int k = 0; k < 4; ++k) {
    const int j = (k << 7) + sj;
    float4 x = *(const float4*)(vpb + (size_t)j * DD + sc);
    *(float4*)&vs[j * 20 + sc] = x;
  }
  __syncthreads();

#pragma unroll 1
  for (int s = 0; s < 16; ++s) {
    float4 r0, r1, r2, r3;
    if (s < 15) {  // issue next sub-chunk loads BEFORE compute
      const int dn = (s + 1) << 4;
      r0 = *(const float4*)(vpb + (size_t)(sj)       * DD + dn + sc);
      r1 = *(const float4*)(vpb + (size_t)(128 + sj) * DD + dn + sc);
      r2 = *(const float4*)(vpb + (size_t)(256 + sj) * DD + dn + sc);
      r3 = *(const float4*)(vpb + (size_t)(384 + sj) * DD + dn + sc);
    }

    const float* vrow = &vs[t * 20];
    const int dbase = s << 4;
#pragma unroll
    for (int d4 = 0; d4 < 4; ++d4) {
      float4 v4 = *(const float4*)&vrow[d4 << 2];
#pragma unroll
      for (int i = 0; i < 2; ++i) {
        float4 q4 = *(const float4*)(qb + i * DD + dbase + (d4 << 2));
        float a = q4.x * v4.x, b = q4.y * v4.y;
        float c = q4.z * v4.z, d = q4.w * v4.w;
        float sab = a + b,  scd = c + d;
        float Q1 = fmaf(a, b, sab + 1.f);   // (1+a)(1+b)
        float Q2 = fmaf(c, d, scd + 1.f);   // (1+c)(1+d)
        float P1 = sab + 2.f, P2 = scd + 2.f;
        float N  = fmaf(P2, Q1, P1 * Q2);
        float r  = fmaf(N, fast_rcp(Q1 * Q2), (i == 0) ? acc0 : acc1);
        if (i == 0) acc0 = r; else acc1 = r;
      }
    }
    __syncthreads();  // all reads of current sub-chunk done
    if (s < 15) {
      *(float4*)&vs[(sj)       * 20 + sc] = r0;
      *(float4*)&vs[(128 + sj) * 20 + sc] = r1;
      *(float4*)&vs[(256 + sj) * 20 + sc] = r2;
      *(float4*)&vs[(384 + sj) * 20 + sc] = r3;
      __syncthreads();  // next sub-chunk resident
    }
  }

  // ---- scores -> alg (aliases vs; loop fully fenced) ----
  alg[t]       = acc0;
  alg[512 + t] = acc1;
  __syncthreads();

  // ---- softmax over j: wave wv (<2) owns row wv exclusively ----
  // score = 256 - 2*S -> max(score) <-> min(S); w = exp2(CC*(Smin - S))
  if (wv < 2) {
    float s[8];
#pragma unroll
    for (int c = 0; c < 8; ++c) s[c] = alg[(wv << 9) + (c << 6) + lane];
    float mn = s[0];
#pragma unroll
    for (int c = 1; c < 8; ++c) mn = fminf(mn, s[c]);
#pragma unroll
    for (int m = 1; m < 64; m <<= 1) mn = fminf(mn, __shfl_xor(mn, m, 64));

    const float CC = 2.8853900817779268f;  // 2*log2(e)
    float p[8];
    float sum = 0.f;
#pragma unroll
    for (int c = 0; c < 8; ++c) { p[c] = fast_exp2(CC * (mn - s[c])); sum += p[c]; }
#pragma unroll
    for (int m = 1; m < 64; m <<= 1) sum += __shfl_xor(sum, m, 64);
    const float inv = fast_rcp(sum);
#pragma unroll
    for (int c = 0; c < 8; ++c) alg[(wv << 9) + (c << 6) + lane] = p[c] * inv;
  }
  __syncthreads();

  // ---- alignment_t write: out2[b][j][i0..i0+1], one float2 per thread ----
  {
    const int j = t;  // 0..511
    float2 av = make_float2(alg[j], alg[512 + j]);
    *(float2*)(out2 + (size_t)(bb * TV + j) * TQ + i0) = av;
  }

  // ---- context, j-split: thread (f, jh) does 256 j's for BOTH rows ----
  const int f  = t & 255;
  const int jh = t >> 8;          // j-half: [jh*256, jh*256+256)
  float c0 = 0.f, c1 = 0.f;       // partial ctx for rows 0,1
  const float* vb = value + (size_t)bb * TV * DD;
  const int jbeg = jh << 8;
#pragma unroll 4
  for (int j = jbeg; j < jbeg + 256; j += 4) {
    float v0 = vb[(size_t)(j + 0) * DD + f];
    float v1 = vb[(size_t)(j + 1) * DD + f];
    float v2 = vb[(size_t)(j + 2) * DD + f];
    float v3 = vb[(size_t)(j + 3) * DD + f];
    float4 a0 = *(const float4*)&alg[j];
    float4 a1 = *(const float4*)&alg[512 + j];
    c0 += a0.x * v0 + a0.y * v1 + a0.z * v2 + a0.w * v3;
    c1 += a1.x * v0 + a1.y * v1 + a1.z * v2 + a1.w * v3;
  }
  part[(jh << 9) + f]       = c0;   // part[jh][row0][f]
  part[(jh << 9) + 256 + f] = c1;   // part[jh][row1][f]
  __syncthreads();

  // ---- combine halves + write [ctx | query]: thread t -> (row = jh, f) ----
  {
    const int row = jh;
    const float cfull = part[(row << 8) + f] + part[512 + (row << 8) + f];
    const float* qg = query + (size_t)(bb * TQ + i0) * DD;
    float* o = out1 + (size_t)(bb * TQ + i0) * (2 * DD);
    o[row * 512 + f]       = cfull;
    o[row * 512 + 256 + f] = qg[row * DD + f];
  }
}

// ---------------------------------------------------------------------------
extern "C" void kernel_launch(void* const* d_in, const int* in_sizes, int n_in,
                              void* d_out, int out_size, void* d_ws, size_t ws_size,
                              hipStream_t stream) {
  const float* query = (const float*)d_in[0];  // [8,256,256]
  const float* value = (const float*)d_in[1];  // [8,512,256]
  const float* W1    = (const float*)d_in[2];  // [256,256]
  const float* b1    = (const float*)d_in[3];  // [256]
  const float* W2    = (const float*)d_in[4];  // [256,256]
  const float* b2    = (const float*)d_in[5];  // [256]

  float* out1 = (float*)d_out;                     // context concat [8,256,512]
  float* out2 = out1 + (size_t)B_ * TQ * 2 * DD;   // alignment_t   [8,512,256]

  float* qp = (float*)d_ws;                        // Eq: 2048*256 floats
  float* vp = qp + (size_t)B_ * TQ * DD;           // Ev: 4096*256 floats

  const float SC = 2.8853900817779268f;  // 2*log2(e): exp(2x) = exp2(SC*x)

  proj_fused<<<dim3(96, 4), 256, 0, stream>>>(query, value, W1, b1, W2, b2, qp, vp, SC);
  attn_kernel<<<dim3(B_ * (TQ / 2)), 512, 0, stream>>>(qp, vp, value, query, out1, out2);
}

// Round 11
// 148.222 us; speedup vs baseline: 1.4794x; 1.4794x over previous
//
#include <hip/hip_runtime.h>

#define B_  8
#define TQ  256
#define TV  512
#define DD  256

__device__ __forceinline__ float fast_exp2(float x) {
#if __has_builtin(__builtin_amdgcn_exp2f)
  return __builtin_amdgcn_exp2f(x);
#else
  return __exp2f(x);
#endif
}
__device__ __forceinline__ float fast_rcp(float x) {
#if __has_builtin(__builtin_amdgcn_rcpf)
  return __builtin_amdgcn_rcpf(x);
#else
  return 1.0f / x;
#endif
}

// ---------------------------------------------------------------------------
// Fused projections with EXP epilogue (identical to rounds 8/9 — validated):
//   Eq = exp2(SC*(query@W1 + b1)),  Ev = exp2(SC*(value@W2 + b2))
// ---------------------------------------------------------------------------
__global__ __launch_bounds__(256) void proj_fused(
    const float* __restrict__ query, const float* __restrict__ value,
    const float* __restrict__ W1, const float* __restrict__ b1,
    const float* __restrict__ W2, const float* __restrict__ b2,
    float* __restrict__ qp, float* __restrict__ vp, float scale) {
  __shared__ float As[2][32][64];  // [p][k][m ^ sw(k)]
  __shared__ float Bs[2][32][64];  // [p][k][n]
  const int t  = threadIdx.x;
  const int rt = blockIdx.x;
  const int bn = blockIdx.y << 6;

  const float* A; const float* W; const float* bias; float* out; int row0;
  if (rt < 32) { row0 = rt << 6;        A = query; W = W1; bias = b1; out = qp; }
  else         { row0 = (rt - 32) << 6; A = value; W = W2; bias = b2; out = vp; }

  const int tx = t & 15, ty = t >> 4;
  const int aar = t >> 3, aac = (t & 7) << 2;
  const int bbr = t >> 4, bbc = (t & 15) << 2;

  float4 ra[2], rb[2];
#pragma unroll
  for (int it = 0; it < 2; ++it) {
    ra[it] = *(const float4*)(A + (size_t)(row0 + (it << 5) + aar) * DD + aac);
    rb[it] = *(const float4*)(W + (size_t)((it << 4) + bbr) * DD + bn + bbc);
  }
#pragma unroll
  for (int it = 0; it < 2; ++it) {
    const int m = (it << 5) + aar;
#pragma unroll
    for (int c = 0; c < 4; ++c) {
      const int k = aac + c;
      As[0][k][m ^ (((k >> 2) & 7) << 2)] = (&ra[it].x)[c];
    }
    *(float4*)&Bs[0][(it << 4) + bbr][bbc] = rb[it];
  }
  __syncthreads();

  float acc[4][4] = {{0.f,0.f,0.f,0.f},{0.f,0.f,0.f,0.f},
                     {0.f,0.f,0.f,0.f},{0.f,0.f,0.f,0.f}};
  int p = 0;

  for (int k0 = 0; k0 < 256; k0 += 32) {
    const bool more = (k0 + 32) < 256;
    if (more) {
#pragma unroll
      for (int it = 0; it < 2; ++it) {
        ra[it] = *(const float4*)(A + (size_t)(row0 + (it << 5) + aar) * DD + k0 + 32 + aac);
        rb[it] = *(const float4*)(W + (size_t)(k0 + 32 + (it << 4) + bbr) * DD + bn + bbc);
      }
    }
#pragma unroll
    for (int k = 0; k < 32; ++k) {
      float4 aq = *(const float4*)&As[p][k][(ty << 2) ^ (((k >> 2) & 7) << 2)];
      float4 bq = *(const float4*)&Bs[p][k][tx << 2];
      acc[0][0] = fmaf(aq.x, bq.x, acc[0][0]); acc[0][1] = fmaf(aq.x, bq.y, acc[0][1]);
      acc[0][2] = fmaf(aq.x, bq.z, acc[0][2]); acc[0][3] = fmaf(aq.x, bq.w, acc[0][3]);
      acc[1][0] = fmaf(aq.y, bq.x, acc[1][0]); acc[1][1] = fmaf(aq.y, bq.y, acc[1][1]);
      acc[1][2] = fmaf(aq.y, bq.z, acc[1][2]); acc[1][3] = fmaf(aq.y, bq.w, acc[1][3]);
      acc[2][0] = fmaf(aq.z, bq.x, acc[2][0]); acc[2][1] = fmaf(aq.z, bq.y, acc[2][1]);
      acc[2][2] = fmaf(aq.z, bq.z, acc[2][2]); acc[2][3] = fmaf(aq.z, bq.w, acc[2][3]);
      acc[3][0] = fmaf(aq.w, bq.x, acc[3][0]); acc[3][1] = fmaf(aq.w, bq.y, acc[3][1]);
      acc[3][2] = fmaf(aq.w, bq.z, acc[3][2]); acc[3][3] = fmaf(aq.w, bq.w, acc[3][3]);
    }
    if (more) {
      const int q = p ^ 1;
#pragma unroll
      for (int it = 0; it < 2; ++it) {
        const int m = (it << 5) + aar;
#pragma unroll
        for (int c = 0; c < 4; ++c) {
          const int k = aac + c;
          As[q][k][m ^ (((k >> 2) & 7) << 2)] = (&ra[it].x)[c];
        }
        *(float4*)&Bs[q][(it << 4) + bbr][bbc] = rb[it];
      }
      __syncthreads();
      p = q;
    }
  }

  float4 bvv = *(const float4*)&bias[bn + (tx << 2)];
#pragma unroll
  for (int r = 0; r < 4; ++r) {
    float4 o;
    o.x = fast_exp2(scale * (acc[r][0] + bvv.x));
    o.y = fast_exp2(scale * (acc[r][1] + bvv.y));
    o.z = fast_exp2(scale * (acc[r][2] + bvv.z));
    o.w = fast_exp2(scale * (acc[r][3] + bvv.w));
    *(float4*)(out + (size_t)(row0 + (ty << 2) + r) * DD + bn + (tx << 2)) = o;
  }
}

// ---------------------------------------------------------------------------
// Fused score + softmax + context + concat + transposed alignment.
// 1024 blocks x 512 threads (8 waves), 2 q-rows per block.
// LDS = single 512x20 buffer = 40960 B. Occupancy comes from ACTUAL VGPR
// use: __launch_bounds__(512, 4) (cap 128, no allocator squeeze) — round 9
// measured 52 VGPRs for a heavier variant, so actual <= 64 here -> HW can
// run 8 waves/SIMD -> 4 blocks/CU (LDS-limited), the occupancy round 10
// measured (69%) WITHOUT round 10's forced-32-VGPR scratch spill.
// 16 sub-chunks of 16 d, single-buffered: issue next loads FIRST (regs
// r0..r3), compute current, barrier, write, barrier.
// q reads wave-uniform -> scalar path, no q LDS traffic.
// Context phase j-split: thread (f = t&255, jh = t>>8) covers 256 j's for
// BOTH rows (value slab read once per block), partials combined via LDS.
// Math (Eq,Ev; x = Eq*Ev): tanh sum via quad-rcp; score = 256 - 2*S.
// ---------------------------------------------------------------------------
__global__ __launch_bounds__(512, 4) void attn_kernel(
    const float* __restrict__ qp, const float* __restrict__ vp,
    const float* __restrict__ value, const float* __restrict__ query,
    float* __restrict__ out1, float* __restrict__ out2) {
  __shared__ float vs[512 * 20];  // 40960 B; aliased as alg[2][512] + part after loop
  float* alg = vs;                 // alg[i*512 + j], 1024 words
  float* part = vs + 2048;         // part[jh*512 + row*256 + f], 1024 words

  const int t    = threadIdx.x;
  const int lane = t & 63;
  const int wv   = t >> 6;        // 0..7
  const int bb   = blockIdx.x & 7;          // batch -> XCD locality
  const int i0   = (blockIdx.x >> 3) << 1;  // first of this block's 2 q-rows

  const float* vpb = vp + (size_t)bb * TV * DD;
  const float* qb  = qp + (size_t)(bb * TQ + i0) * DD;  // wave-uniform reads

  const int sj = t >> 2;          // staging row base 0..127
  const int sc = (t & 3) << 2;    // staging col 0/4/8/12 (64B per lane-quad)

  float acc0 = 0.f, acc1 = 0.f;

  // stage sub-chunk 0
#pragma unroll
  for (int k = 0; k < 4; ++k) {
    const int j = (k << 7) + sj;
    float4 x = *(const float4*)(vpb + (size_t)j * DD + sc);
    *(float4*)&vs[j * 20 + sc] = x;
  }
  __syncthreads();

#pragma unroll 1
  for (int s = 0; s < 16; ++s) {
    float4 r0, r1, r2, r3;
    if (s < 15) {  // issue next sub-chunk loads BEFORE compute
      const int dn = (s + 1) << 4;
      r0 = *(const float4*)(vpb + (size_t)(sj)       * DD + dn + sc);
      r1 = *(const float4*)(vpb + (size_t)(128 + sj) * DD + dn + sc);
      r2 = *(const float4*)(vpb + (size_t)(256 + sj) * DD + dn + sc);
      r3 = *(const float4*)(vpb + (size_t)(384 + sj) * DD + dn + sc);
    }

    const float* vrow = &vs[t * 20];
    const int dbase = s << 4;
#pragma unroll
    for (int d4 = 0; d4 < 4; ++d4) {
      float4 v4 = *(const float4*)&vrow[d4 << 2];
#pragma unroll
      for (int i = 0; i < 2; ++i) {
        float4 q4 = *(const float4*)(qb + i * DD + dbase + (d4 << 2));
        float a = q4.x * v4.x, b = q4.y * v4.y;
        float c = q4.z * v4.z, d = q4.w * v4.w;
        float sab = a + b,  scd = c + d;
        float Q1 = fmaf(a, b, sab + 1.f);   // (1+a)(1+b)
        float Q2 = fmaf(c, d, scd + 1.f);   // (1+c)(1+d)
        float P1 = sab + 2.f, P2 = scd + 2.f;
        float N  = fmaf(P2, Q1, P1 * Q2);
        float r  = fmaf(N, fast_rcp(Q1 * Q2), (i == 0) ? acc0 : acc1);
        if (i == 0) acc0 = r; else acc1 = r;
      }
    }
    __syncthreads();  // all reads of current sub-chunk done
    if (s < 15) {
      *(float4*)&vs[(sj)       * 20 + sc] = r0;
      *(float4*)&vs[(128 + sj) * 20 + sc] = r1;
      *(float4*)&vs[(256 + sj) * 20 + sc] = r2;
      *(float4*)&vs[(384 + sj) * 20 + sc] = r3;
      __syncthreads();  // next sub-chunk resident
    }
  }

  // ---- scores -> alg (aliases vs; loop fully fenced) ----
  alg[t]       = acc0;
  alg[512 + t] = acc1;
  __syncthreads();

  // ---- softmax over j: wave wv (<2) owns row wv exclusively ----
  // score = 256 - 2*S -> max(score) <-> min(S); w = exp2(CC*(Smin - S))
  if (wv < 2) {
    float s[8];
#pragma unroll
    for (int c = 0; c < 8; ++c) s[c] = alg[(wv << 9) + (c << 6) + lane];
    float mn = s[0];
#pragma unroll
    for (int c = 1; c < 8; ++c) mn = fminf(mn, s[c]);
#pragma unroll
    for (int m = 1; m < 64; m <<= 1) mn = fminf(mn, __shfl_xor(mn, m, 64));

    const float CC = 2.8853900817779268f;  // 2*log2(e)
    float p[8];
    float sum = 0.f;
#pragma unroll
    for (int c = 0; c < 8; ++c) { p[c] = fast_exp2(CC * (mn - s[c])); sum += p[c]; }
#pragma unroll
    for (int m = 1; m < 64; m <<= 1) sum += __shfl_xor(sum, m, 64);
    const float inv = fast_rcp(sum);
#pragma unroll
    for (int c = 0; c < 8; ++c) alg[(wv << 9) + (c << 6) + lane] = p[c] * inv;
  }
  __syncthreads();

  // ---- alignment_t write: out2[b][j][i0..i0+1], one float2 per thread ----
  {
    const int j = t;  // 0..511
    float2 av = make_float2(alg[j], alg[512 + j]);
    *(float2*)(out2 + (size_t)(bb * TV + j) * TQ + i0) = av;
  }

  // ---- context, j-split: thread (f, jh) does 256 j's for BOTH rows ----
  const int f  = t & 255;
  const int jh = t >> 8;          // j-half: [jh*256, jh*256+256)
  float c0 = 0.f, c1 = 0.f;       // partial ctx for rows 0,1
  const float* vb = value + (size_t)bb * TV * DD;
  const int jbeg = jh << 8;
#pragma unroll 4
  for (int j = jbeg; j < jbeg + 256; j += 4) {
    float v0 = vb[(size_t)(j + 0) * DD + f];
    float v1 = vb[(size_t)(j + 1) * DD + f];
    float v2 = vb[(size_t)(j + 2) * DD + f];
    float v3 = vb[(size_t)(j + 3) * DD + f];
    float4 a0 = *(const float4*)&alg[j];
    float4 a1 = *(const float4*)&alg[512 + j];
    c0 += a0.x * v0 + a0.y * v1 + a0.z * v2 + a0.w * v3;
    c1 += a1.x * v0 + a1.y * v1 + a1.z * v2 + a1.w * v3;
  }
  part[(jh << 9) + f]       = c0;   // part[jh][row0][f]
  part[(jh << 9) + 256 + f] = c1;   // part[jh][row1][f]
  __syncthreads();

  // ---- combine halves + write [ctx | query]: thread t -> (row = jh, f) ----
  {
    const int row = jh;
    const float cfull = part[(row << 8) + f] + part[512 + (row << 8) + f];
    const float* qg = query + (size_t)(bb * TQ + i0) * DD;
    float* o = out1 + (size_t)(bb * TQ + i0) * (2 * DD);
    o[row * 512 + f]       = cfull;
    o[row * 512 + 256 + f] = qg[row * DD + f];
  }
}

// ---------------------------------------------------------------------------
extern "C" void kernel_launch(void* const* d_in, const int* in_sizes, int n_in,
                              void* d_out, int out_size, void* d_ws, size_t ws_size,
                              hipStream_t stream) {
  const float* query = (const float*)d_in[0];  // [8,256,256]
  const float* value = (const float*)d_in[1];  // [8,512,256]
  const float* W1    = (const float*)d_in[2];  // [256,256]
  const float* b1    = (const float*)d_in[3];  // [256]
  const float* W2    = (const float*)d_in[4];  // [256,256]
  const float* b2    = (const float*)d_in[5];  // [256]

  float* out1 = (float*)d_out;                     // context concat [8,256,512]
  float* out2 = out1 + (size_t)B_ * TQ * 2 * DD;   // alignment_t   [8,512,256]

  float* qp = (float*)d_ws;                        // Eq: 2048*256 floats
  float* vp = qp + (size_t)B_ * TQ * DD;           // Ev: 4096*256 floats

  const float SC = 2.8853900817779268f;  // 2*log2(e): exp(2x) = exp2(SC*x)

  proj_fused<<<dim3(96, 4), 256, 0, stream>>>(query, value, W1, b1, W2, b2, qp, vp, SC);
  attn_kernel<<<dim3(B_ * (TQ / 2)), 512, 0, stream>>>(qp, vp, value, query, out1, out2);
}

// Round 12
// 137.033 us; speedup vs baseline: 1.6002x; 1.0817x over previous
//
#include <hip/hip_runtime.h>

#define B_  8
#define TQ  256
#define TV  512
#define DD  256
#define ALGS 520  // alg row stride: quad-write banks {j,j+8,j+16,j+24} -> <=2-way = free

__device__ __forceinline__ float fast_exp2(float x) {
#if __has_builtin(__builtin_amdgcn_exp2f)
  return __builtin_amdgcn_exp2f(x);
#else
  return __exp2f(x);
#endif
}
__device__ __forceinline__ float fast_rcp(float x) {
#if __has_builtin(__builtin_amdgcn_rcpf)
  return __builtin_amdgcn_rcpf(x);
#else
  return 1.0f / x;
#endif
}

// ---------------------------------------------------------------------------
// Fused projections with EXP epilogue (identical to rounds 8-11 — validated):
//   Eq = exp2(SC*(query@W1 + b1)),  Ev = exp2(SC*(value@W2 + b2))
// ---------------------------------------------------------------------------
__global__ __launch_bounds__(256) void proj_fused(
    const float* __restrict__ query, const float* __restrict__ value,
    const float* __restrict__ W1, const float* __restrict__ b1,
    const float* __restrict__ W2, const float* __restrict__ b2,
    float* __restrict__ qp, float* __restrict__ vp, float scale) {
  __shared__ float As[2][32][64];  // [p][k][m ^ sw(k)]
  __shared__ float Bs[2][32][64];  // [p][k][n]
  const int t  = threadIdx.x;
  const int rt = blockIdx.x;
  const int bn = blockIdx.y << 6;

  const float* A; const float* W; const float* bias; float* out; int row0;
  if (rt < 32) { row0 = rt << 6;        A = query; W = W1; bias = b1; out = qp; }
  else         { row0 = (rt - 32) << 6; A = value; W = W2; bias = b2; out = vp; }

  const int tx = t & 15, ty = t >> 4;
  const int aar = t >> 3, aac = (t & 7) << 2;
  const int bbr = t >> 4, bbc = (t & 15) << 2;

  float4 ra[2], rb[2];
#pragma unroll
  for (int it = 0; it < 2; ++it) {
    ra[it] = *(const float4*)(A + (size_t)(row0 + (it << 5) + aar) * DD + aac);
    rb[it] = *(const float4*)(W + (size_t)((it << 4) + bbr) * DD + bn + bbc);
  }
#pragma unroll
  for (int it = 0; it < 2; ++it) {
    const int m = (it << 5) + aar;
#pragma unroll
    for (int c = 0; c < 4; ++c) {
      const int k = aac + c;
      As[0][k][m ^ (((k >> 2) & 7) << 2)] = (&ra[it].x)[c];
    }
    *(float4*)&Bs[0][(it << 4) + bbr][bbc] = rb[it];
  }
  __syncthreads();

  float acc[4][4] = {{0.f,0.f,0.f,0.f},{0.f,0.f,0.f,0.f},
                     {0.f,0.f,0.f,0.f},{0.f,0.f,0.f,0.f}};
  int p = 0;

  for (int k0 = 0; k0 < 256; k0 += 32) {
    const bool more = (k0 + 32) < 256;
    if (more) {
#pragma unroll
      for (int it = 0; it < 2; ++it) {
        ra[it] = *(const float4*)(A + (size_t)(row0 + (it << 5) + aar) * DD + k0 + 32 + aac);
        rb[it] = *(const float4*)(W + (size_t)(k0 + 32 + (it << 4) + bbr) * DD + bn + bbc);
      }
    }
#pragma unroll
    for (int k = 0; k < 32; ++k) {
      float4 aq = *(const float4*)&As[p][k][(ty << 2) ^ (((k >> 2) & 7) << 2)];
      float4 bq = *(const float4*)&Bs[p][k][tx << 2];
      acc[0][0] = fmaf(aq.x, bq.x, acc[0][0]); acc[0][1] = fmaf(aq.x, bq.y, acc[0][1]);
      acc[0][2] = fmaf(aq.x, bq.z, acc[0][2]); acc[0][3] = fmaf(aq.x, bq.w, acc[0][3]);
      acc[1][0] = fmaf(aq.y, bq.x, acc[1][0]); acc[1][1] = fmaf(aq.y, bq.y, acc[1][1]);
      acc[1][2] = fmaf(aq.y, bq.z, acc[1][2]); acc[1][3] = fmaf(aq.y, bq.w, acc[1][3]);
      acc[2][0] = fmaf(aq.z, bq.x, acc[2][0]); acc[2][1] = fmaf(aq.z, bq.y, acc[2][1]);
      acc[2][2] = fmaf(aq.z, bq.z, acc[2][2]); acc[2][3] = fmaf(aq.z, bq.w, acc[2][3]);
      acc[3][0] = fmaf(aq.w, bq.x, acc[3][0]); acc[3][1] = fmaf(aq.w, bq.y, acc[3][1]);
      acc[3][2] = fmaf(aq.w, bq.z, acc[3][2]); acc[3][3] = fmaf(aq.w, bq.w, acc[3][3]);
    }
    if (more) {
      const int q = p ^ 1;
#pragma unroll
      for (int it = 0; it < 2; ++it) {
        const int m = (it << 5) + aar;
#pragma unroll
        for (int c = 0; c < 4; ++c) {
          const int k = aac + c;
          As[q][k][m ^ (((k >> 2) & 7) << 2)] = (&ra[it].x)[c];
        }
        *(float4*)&Bs[q][(it << 4) + bbr][bbc] = rb[it];
      }
      __syncthreads();
      p = q;
    }
  }

  float4 bvv = *(const float4*)&bias[bn + (tx << 2)];
#pragma unroll
  for (int r = 0; r < 4; ++r) {
    float4 o;
    o.x = fast_exp2(scale * (acc[r][0] + bvv.x));
    o.y = fast_exp2(scale * (acc[r][1] + bvv.y));
    o.z = fast_exp2(scale * (acc[r][2] + bvv.z));
    o.w = fast_exp2(scale * (acc[r][3] + bvv.w));
    *(float4*)(out + (size_t)(row0 + (ty << 2) + r) * DD + bn + (tx << 2)) = o;
  }
}

// ---------------------------------------------------------------------------
// Fused score + softmax + context + concat + transposed alignment.
// 512 blocks x 512 threads (8 waves), 4 q-rows per block, TI=4 (minimal
// L2 traffic: Ev+value read once per block = 512 MB total).
// NO LDS STAGING, NO SCORE-LOOP BARRIERS: lane = (jj = lane>>2 -> row,
// dq = lane&3 -> d-quarter phase). A wave's 64 lanes load 16 Ev rows x 64 B
// contiguous per inst (16 L1 segments, 4x better than lane=j scatter);
// rows stay L2-resident across the d-loop. d(k,dq) = 16k + 4dq + 0..3.
// q fragments from a 4 KB LDS tile: per inst 4 distinct addrs x 16-way
// broadcast = conflict-free. Each lane accumulates acc[4 rows][4 j-groups]
// over its d-subset; ONE 2-step quad butterfly at the end (32 shuffles
// total) completes the d-reduction; lane writes the i = dq score slice.
// Math (Eq,Ev; x = Eq*Ev): quad-rcp; score = 256 - 2*S; min-S softmax.
// ---------------------------------------------------------------------------
__global__ __launch_bounds__(512, 4) void attn_kernel(
    const float* __restrict__ qp, const float* __restrict__ vp,
    const float* __restrict__ value, const float* __restrict__ query,
    float* __restrict__ out1, float* __restrict__ out2) {
  __shared__ float qs[4 * 256];    // Eq rows, 4 KB
  __shared__ float alg[4 * ALGS];  // raw S then alignment, 8.3 KB

  const int t    = threadIdx.x;
  const int lane = t & 63;
  const int wv   = t >> 6;        // 0..7
  const int jj   = lane >> 2;     // 0..15: row within wave's 16-row group
  const int dq   = lane & 3;      // d-quarter phase
  const int bb   = blockIdx.x & 7;          // batch -> XCD locality
  const int i0   = (blockIdx.x >> 3) << 2;  // first of 4 q-rows

  const float* vpb = vp + (size_t)bb * TV * DD;
  const float* qb  = qp + (size_t)(bb * TQ + i0) * DD;

  // stage 4 Eq rows into LDS (coalesced)
  if (t < 256) {
    const int qi = t >> 6, qc = (t & 63) << 2;
    *(float4*)&qs[qi * 256 + qc] = *(const float4*)(qb + (size_t)qi * DD + qc);
  }
  __syncthreads();

  // per-lane Ev row bases: j(jg) = jg*128 + wv*16 + jj
  const int jb = (wv << 4) + jj;
  const float* vr0 = vpb + (size_t)jb * DD + (dq << 2);
  const float* vr1 = vr0 + 128 * DD;
  const float* vr2 = vr0 + 256 * DD;
  const float* vr3 = vr0 + 384 * DD;
  const float* qlane = qs + (dq << 2);

  float acc[4][4] = {{0.f,0.f,0.f,0.f},{0.f,0.f,0.f,0.f},
                     {0.f,0.f,0.f,0.f},{0.f,0.f,0.f,0.f}};

#pragma unroll 2
  for (int k = 0; k < 16; ++k) {
    const int doff = k << 4;  // 16 floats per k-step (imm offsets <= 960 B)
    float4 q0 = *(const float4*)(qlane + 0 * 256 + doff);
    float4 q1 = *(const float4*)(qlane + 1 * 256 + doff);
    float4 q2 = *(const float4*)(qlane + 2 * 256 + doff);
    float4 q3 = *(const float4*)(qlane + 3 * 256 + doff);
#pragma unroll
    for (int jg = 0; jg < 4; ++jg) {
      const float* vrp = (jg == 0) ? vr0 : (jg == 1) ? vr1 : (jg == 2) ? vr2 : vr3;
      float4 v4 = *(const float4*)(vrp + doff);
#pragma unroll
      for (int i = 0; i < 4; ++i) {
        const float4 q4 = (i == 0) ? q0 : (i == 1) ? q1 : (i == 2) ? q2 : q3;
        float a = q4.x * v4.x, b = q4.y * v4.y;
        float c = q4.z * v4.z, d = q4.w * v4.w;
        float sab = a + b,  scd = c + d;
        float Q1 = fmaf(a, b, sab + 1.f);   // (1+a)(1+b)
        float Q2 = fmaf(c, d, scd + 1.f);   // (1+c)(1+d)
        float N  = fmaf(scd + 2.f, Q1, (sab + 2.f) * Q2);
        acc[i][jg] = fmaf(N, fast_rcp(Q1 * Q2), acc[i][jg]);
      }
    }
  }

  // quad butterfly (once): combine the 4 d-quarter partials within each jj
#pragma unroll
  for (int i = 0; i < 4; ++i)
#pragma unroll
    for (int jg = 0; jg < 4; ++jg) {
      acc[i][jg] += __shfl_xor(acc[i][jg], 1, 64);
      acc[i][jg] += __shfl_xor(acc[i][jg], 2, 64);
    }
  // lane writes the i = dq slice (banks <=2-way with ALGS=520)
#pragma unroll
  for (int jg = 0; jg < 4; ++jg) {
    float x = (dq == 0) ? acc[0][jg] : (dq == 1) ? acc[1][jg]
            : (dq == 2) ? acc[2][jg] : acc[3][jg];
    alg[dq * ALGS + (jg << 7) + jb] = x;
  }
  __syncthreads();

  // ---- softmax over j: wave wv (<4) owns row wv exclusively ----
  // score = 256 - 2*S -> max(score) <-> min(S); w = exp2(CC*(Smin - S))
  if (wv < 4) {
    float s[8];
#pragma unroll
    for (int c = 0; c < 8; ++c) s[c] = alg[wv * ALGS + (c << 6) + lane];
    float mn = s[0];
#pragma unroll
    for (int c = 1; c < 8; ++c) mn = fminf(mn, s[c]);
#pragma unroll
    for (int m = 1; m < 64; m <<= 1) mn = fminf(mn, __shfl_xor(mn, m, 64));

    const float CC = 2.8853900817779268f;  // 2*log2(e)
    float p[8];
    float sum = 0.f;
#pragma unroll
    for (int c = 0; c < 8; ++c) { p[c] = fast_exp2(CC * (mn - s[c])); sum += p[c]; }
#pragma unroll
    for (int m = 1; m < 64; m <<= 1) sum += __shfl_xor(sum, m, 64);
    const float inv = fast_rcp(sum);
#pragma unroll
    for (int c = 0; c < 8; ++c) alg[wv * ALGS + (c << 6) + lane] = p[c] * inv;
  }
  __syncthreads();

  // ---- alignment_t write: out2[b][j][i0..i0+3], one float4 per thread ----
  {
    const int j = t;  // 0..511
    float4 av = make_float4(alg[j], alg[ALGS + j], alg[2 * ALGS + j], alg[3 * ALGS + j]);
    *(float4*)(out2 + (size_t)(bb * TV + j) * TQ + i0) = av;
  }

  // ---- context: thread t owns (feature f, row-pair rp) ----
  const int f  = t & 255;
  const int rp = t >> 8;          // 0 or 1 -> rows 2rp, 2rp+1
  float c0 = 0.f, c1 = 0.f;
  const float* vb = value + (size_t)bb * TV * DD;
  const float* a0p = &alg[(2 * rp + 0) * ALGS];
  const float* a1p = &alg[(2 * rp + 1) * ALGS];
#pragma unroll 4
  for (int j = 0; j < TV; j += 4) {
    float v0 = vb[(size_t)(j + 0) * DD + f];
    float v1 = vb[(size_t)(j + 1) * DD + f];
    float v2 = vb[(size_t)(j + 2) * DD + f];
    float v3 = vb[(size_t)(j + 3) * DD + f];
    float4 a0 = *(const float4*)&a0p[j];
    float4 a1 = *(const float4*)&a1p[j];
    c0 += a0.x * v0 + a0.y * v1 + a0.z * v2 + a0.w * v3;
    c1 += a1.x * v0 + a1.y * v1 + a1.z * v2 + a1.w * v3;
  }

  // ---- context-concat output: [ctx | query] per row ----
  const int r0_ = (rp << 1), r1_ = r0_ + 1;
  const float* qg = query + (size_t)(bb * TQ + i0) * DD;
  float* o = out1 + (size_t)(bb * TQ + i0) * (2 * DD);
  o[r0_ * 512 + f] = c0; o[r0_ * 512 + 256 + f] = qg[r0_ * DD + f];
  o[r1_ * 512 + f] = c1; o[r1_ * 512 + 256 + f] = qg[r1_ * DD + f];
}

// ---------------------------------------------------------------------------
extern "C" void kernel_launch(void* const* d_in, const int* in_sizes, int n_in,
                              void* d_out, int out_size, void* d_ws, size_t ws_size,
                              hipStream_t stream) {
  const float* query = (const float*)d_in[0];  // [8,256,256]
  const float* value = (const float*)d_in[1];  // [8,512,256]
  const float* W1    = (const float*)d_in[2];  // [256,256]
  const float* b1    = (const float*)d_in[3];  // [256]
  const float* W2    = (const float*)d_in[4];  // [256,256]
  const float* b2    = (const float*)d_in[5];  // [256]

  float* out1 = (float*)d_out;                     // context concat [8,256,512]
  float* out2 = out1 + (size_t)B_ * TQ * 2 * DD;   // alignment_t   [8,512,256]

  float* qp = (float*)d_ws;                        // Eq: 2048*256 floats
  float* vp = qp + (size_t)B_ * TQ * DD;           // Ev: 4096*256 floats

  const float SC = 2.8853900817779268f;  // 2*log2(e): exp(2x) = exp2(SC*x)

  proj_fused<<<dim3(96, 4), 256, 0, stream>>>(query, value, W1, b1, W2, b2, qp, vp, SC);
  attn_kernel<<<dim3(B_ * (TQ / 4)), 512, 0, stream>>>(qp, vp, value, query, out1, out2);
}